// Round 13
// baseline (323.153 us; speedup 1.0000x reference)
//
#include <hip/hip_runtime.h>
#include <hip/hip_fp16.h>

#define NN 100000
#define NE 1600000
#define INF 4
#define H 128
#define RR 20
#define OUTF 2
#define NB 782            // buckets of 128 nodes: ceil(100000/128)
#define NBP 784           // padded row stride for hist/offs matrices
#define EPB 4096          // edges per partition block (391 blocks -> full occupancy)
#define NBLK ((NE + EPB - 1) / EPB)   // 391
#define ASPLIT 4          // sub-blocks per bucket in layer-1 aggregation

typedef unsigned int uint32;
typedef __attribute__((ext_vector_type(8))) short short8;   // 8 f16 (4 VGPR) MFMA A/B frag
typedef __attribute__((ext_vector_type(4))) float f32x4;    // MFMA C/D frag

// pack two floats to fp16 pair (RNE): x -> low 16, y -> high 16
__device__ inline uint32 pack_f16(float x, float y) {
    return (uint32)__half_as_ushort(__float2half(x)) |
           ((uint32)__half_as_ushort(__float2half(y)) << 16);
}
__device__ inline __half2 bc_h2(uint32 u) {
    union { uint32 u; __half2 h; } c; c.u = u; return c.h;
}

// ---------------- init (pooled/in_size zeroed by hipMemsetAsync) ----------------
__global__ void k_init_nodes(const float* __restrict__ x, int* __restrict__ in_size) {
    int i = blockIdx.x * 256 + threadIdx.x;
    bool pred = false;
    if (i < NN) {
        float x0 = x[(size_t)i * INF + 0];
        float x1 = x[(size_t)i * INF + 1];
        pred = (x0 != 0.f) && (x1 != 0.f);
    }
    unsigned long long m = __ballot(pred);
    if ((threadIdx.x & 63) == 0) {
        int c = __popcll(m);
        if (c) atomicAdd(in_size, c);
    }
}

// ---------------- counting-sort partition (LDS atomics only) --------------------
__global__ void __launch_bounds__(256) k_hist(const int* __restrict__ dst,
                                              int* __restrict__ histG) {
    __shared__ int h[NB];
    int b = blockIdx.x, t = threadIdx.x;
    for (int i = t; i < NB; i += 256) h[i] = 0;
    __syncthreads();
    int e0 = b * EPB, eend = min(e0 + EPB, NE);
    for (int e = e0 + t; e < eend; e += 256) atomicAdd(&h[dst[e] >> 7], 1);
    __syncthreads();
    for (int i = t; i < NB; i += 256) histG[b * NBP + i] = h[i];
}

__global__ void k_btotoffs(const int* __restrict__ histG, int* __restrict__ offs,
                           int* __restrict__ btot) {
    int bkt = blockIdx.x * 256 + threadIdx.x;
    if (bkt >= NB) return;
    int run = 0;
    for (int j = 0; j < NBLK; ++j) {
        int v = histG[j * NBP + bkt];
        offs[j * NBP + bkt] = run;
        run += v;
    }
    btot[bkt] = run;
}

__global__ void __launch_bounds__(1024) k_bbase(const int* __restrict__ btot,
                                                int* __restrict__ bbase) {
    __shared__ int sm[1024];
    int t = threadIdx.x;
    int v = (t < NB) ? btot[t] : 0;
    sm[t] = v;
    __syncthreads();
    for (int off = 1; off < 1024; off <<= 1) {
        int u = (t >= off) ? sm[t - off] : 0;
        __syncthreads();
        sm[t] += u;
        __syncthreads();
    }
    if (t < NB) bbase[t] = sm[t] - v;
    if (t == 0) bbase[NB] = NE;
}

__global__ void __launch_bounds__(256) k_scat2(const int* __restrict__ src,
                                               const int* __restrict__ dst,
                                               const int* __restrict__ offs,
                                               const int* __restrict__ bbase,
                                               uint32* __restrict__ data) {
    __shared__ int cur[NB];
    int b = blockIdx.x, t = threadIdx.x;
    for (int i = t; i < NB; i += 256) cur[i] = offs[b * NBP + i] + bbase[i];
    __syncthreads();
    int e0 = b * EPB, eend = min(e0 + EPB, NE);
    for (int e = e0 + t; e < eend; e += 256) {
        int s = src[e], d = dst[e];
        int p = atomicAdd(&cur[d >> 7], 1);
        data[p] = ((uint32)s << 7) | (uint32)(d & 127);
    }
}

// one block per bucket: histogram -> csr_off/csr_cnt/dinv/xd + node-sorted csr_src.
__global__ void __launch_bounds__(256) k_build(const uint32* __restrict__ data,
                                               const int* __restrict__ bbase,
                                               const float* __restrict__ x,
                                               int* __restrict__ csr_off,
                                               int* __restrict__ csr_cnt,
                                               int* __restrict__ csr_src,
                                               float* __restrict__ dinv,
                                               float4* __restrict__ xd) {
    __shared__ int hist[128], pfx[128], curs[128];
    int bkt = blockIdx.x;
    int t = threadIdx.x;
    int rbeg = bbase[bkt], rend = bbase[bkt + 1];
    if (t < 128) hist[t] = 0;
    __syncthreads();
    for (int j = rbeg + t; j < rend; j += 256)
        atomicAdd(&hist[data[j] & 127], 1);
    __syncthreads();
    if (t < 128) pfx[t] = hist[t];
    __syncthreads();
    for (int off = 1; off < 128; off <<= 1) {
        int u = (t < 128 && t >= off) ? pfx[t - off] : 0;
        __syncthreads();
        if (t < 128) pfx[t] += u;
        __syncthreads();
    }
    int nodeCount = min(128, NN - bkt * 128);
    if (t < nodeCount) {
        int gi = bkt * 128 + t;
        int excl = rbeg + pfx[t] - hist[t];
        csr_off[gi] = excl;
        csr_cnt[gi] = hist[t];
        curs[t] = excl;
        float di = rsqrtf((float)(hist[t] + 1));
        dinv[gi] = di;
        const float4 xv = *(const float4*)(x + (size_t)gi * INF);
        xd[gi] = make_float4(xv.x * di, xv.y * di, xv.z * di, xv.w * di);
    }
    __syncthreads();
    for (int j = rbeg + t; j < rend; j += 256) {
        uint32 r = data[j];
        int p = atomicAdd(&curs[r & 127], 1);
        csr_src[p] = (int)(r >> 7);
    }
}

// ---------------- layer-1 aggregation: 4 blocks per bucket, no atomics ----------
__global__ void __launch_bounds__(256) k_aggx4(const uint32* __restrict__ data,
                                               const int* __restrict__ bbase,
                                               const float4* __restrict__ xd,
                                               float* __restrict__ Axpart) {
    __shared__ float acc[128][4];
    int bkt = blockIdx.x >> 2, sp = blockIdx.x & 3;
    int t = threadIdx.x;
    if (t < 128) { acc[t][0] = 0.f; acc[t][1] = 0.f; acc[t][2] = 0.f; acc[t][3] = 0.f; }
    int rbeg = bbase[bkt], rend = bbase[bkt + 1];
    int len = rend - rbeg;
    int q0 = rbeg + ((long long)len * sp >> 2);
    int q1 = rbeg + ((long long)len * (sp + 1) >> 2);
    __syncthreads();
    for (int j = q0 + t; j < q1; j += 256) {
        uint32 r = data[j];
        int s = (int)(r >> 7), dl = (int)(r & 127);
        const float4 v = xd[s];
        atomicAdd(&acc[dl][0], v.x);
        atomicAdd(&acc[dl][1], v.y);
        atomicAdd(&acc[dl][2], v.z);
        atomicAdd(&acc[dl][3], v.w);
    }
    __syncthreads();
    float* dstp = Axpart + (size_t)blockIdx.x * 512;
    for (int i = t; i < 512; i += 256) dstp[i] = ((const float*)acc)[i];
}

// merge 4 parts + self-term, scale by dinv -> Ax  (all loads/stores coalesced)
__global__ void k_merge(const float* __restrict__ Axpart, const float4* __restrict__ xd,
                        const float* __restrict__ dinv, float4* __restrict__ Ax) {
    int i = blockIdx.x * 256 + threadIdx.x;
    if (i >= NN) return;
    int bkt = i >> 7, nl = i & 127;
    float4 a = xd[i];   // self-loop term
    #pragma unroll
    for (int sp = 0; sp < 4; ++sp) {
        const float4 p = *(const float4*)(Axpart + ((size_t)(bkt * 4 + sp)) * 512 + nl * 4);
        a.x += p.x; a.y += p.y; a.z += p.z; a.w += p.w;
    }
    float di = dinv[i];
    Ax[i] = make_float4(a.x * di, a.y * di, a.z * di, a.w * di);
}

// matvec + tanh + fp16 pack: Yp = pack(tanh(Ax@W1+b1)*dinv), wave per node
__global__ void __launch_bounds__(256) k_mm1b(const float4* __restrict__ Ax,
                                              const float* __restrict__ dinv,
                                              const float* __restrict__ W1,
                                              const float* __restrict__ b1,
                                              uint32* __restrict__ Yp) {
    __shared__ float w1s[4][128];
    __shared__ float b1s[128];
    int t = threadIdx.x;
    if (t < 128) b1s[t] = b1[t];
    ((float*)w1s)[t] = W1[t];
    ((float*)w1s)[256 + t] = W1[256 + t];
    __syncthreads();
    int wid = t >> 6, lane = t & 63;
    int node = blockIdx.x * 4 + wid;
    if (node >= NN) return;
    const float4 a = Ax[node];
    float di = dinv[node];
    int f0 = lane * 2;
    float d0 = b1s[f0]     + a.x * w1s[0][f0]     + a.y * w1s[1][f0]
                           + a.z * w1s[2][f0]     + a.w * w1s[3][f0];
    float d1 = b1s[f0 + 1] + a.x * w1s[0][f0 + 1] + a.y * w1s[1][f0 + 1]
                           + a.z * w1s[2][f0 + 1] + a.w * w1s[3][f0 + 1];
    Yp[(size_t)node * 64 + lane] = pack_f16(tanhf(d0) * di, tanhf(d1) * di);
}

// ---------------- layer 2 gather: Zp = f16( dinv[i]*(sum Yp[s] + Yp[i]) ) -------
// one wave per node; lane = (edge-group eg, 16B segment seg): one dwordx4 fetches
// FOUR edges' row-chunks; unroll x4 -> 4 loads in flight (MLP probe of the
// vmem-pipe ceiling: 435MB useful reads at ~6.7 TB/s).
__global__ void k_aggy(const uint32* __restrict__ Yp, const int* __restrict__ csr_off,
                       const int* __restrict__ csr_cnt, const int* __restrict__ csr_src,
                       const float* __restrict__ dinv, uint32* __restrict__ Zp) {
    int wid = threadIdx.x >> 6;
    int lane = threadIdx.x & 63;
    int i = blockIdx.x * 4 + wid;
    if (i >= NN) return;
    int b = csr_off[i];
    int n = csr_cnt[i];
    int eg = lane >> 4, seg = lane & 15;

    __half2 h0 = bc_h2(0u), h1 = bc_h2(0u), h2 = bc_h2(0u), h3 = bc_h2(0u);
    int j = 0;
    for (; j + 16 <= n; j += 16) {
        int s0 = csr_src[b + j + eg];
        int s1 = csr_src[b + j + 4 + eg];
        int s2 = csr_src[b + j + 8 + eg];
        int s3 = csr_src[b + j + 12 + eg];
        uint4 v0 = *(const uint4*)(Yp + (size_t)s0 * 64 + seg * 4);
        uint4 v1 = *(const uint4*)(Yp + (size_t)s1 * 64 + seg * 4);
        uint4 v2 = *(const uint4*)(Yp + (size_t)s2 * 64 + seg * 4);
        uint4 v3 = *(const uint4*)(Yp + (size_t)s3 * 64 + seg * 4);
        h0 = __hadd2(h0, bc_h2(v0.x)); h1 = __hadd2(h1, bc_h2(v0.y));
        h2 = __hadd2(h2, bc_h2(v0.z)); h3 = __hadd2(h3, bc_h2(v0.w));
        h0 = __hadd2(h0, bc_h2(v1.x)); h1 = __hadd2(h1, bc_h2(v1.y));
        h2 = __hadd2(h2, bc_h2(v1.z)); h3 = __hadd2(h3, bc_h2(v1.w));
        h0 = __hadd2(h0, bc_h2(v2.x)); h1 = __hadd2(h1, bc_h2(v2.y));
        h2 = __hadd2(h2, bc_h2(v2.z)); h3 = __hadd2(h3, bc_h2(v2.w));
        h0 = __hadd2(h0, bc_h2(v3.x)); h1 = __hadd2(h1, bc_h2(v3.y));
        h2 = __hadd2(h2, bc_h2(v3.z)); h3 = __hadd2(h3, bc_h2(v3.w));
    }
    for (; j + 8 <= n; j += 8) {
        int s0 = csr_src[b + j + eg];
        int s1 = csr_src[b + j + 4 + eg];
        uint4 v0 = *(const uint4*)(Yp + (size_t)s0 * 64 + seg * 4);
        uint4 v1 = *(const uint4*)(Yp + (size_t)s1 * 64 + seg * 4);
        h0 = __hadd2(h0, bc_h2(v0.x)); h1 = __hadd2(h1, bc_h2(v0.y));
        h2 = __hadd2(h2, bc_h2(v0.z)); h3 = __hadd2(h3, bc_h2(v0.w));
        h0 = __hadd2(h0, bc_h2(v1.x)); h1 = __hadd2(h1, bc_h2(v1.y));
        h2 = __hadd2(h2, bc_h2(v1.z)); h3 = __hadd2(h3, bc_h2(v1.w));
    }
    for (; j < n; j += 4) {
        int jj = j + eg;
        bool valid = jj < n;
        int s = valid ? csr_src[b + jj] : i;   // safe address; contribution masked
        uint4 v = *(const uint4*)(Yp + (size_t)s * 64 + seg * 4);
        if (valid) {
            h0 = __hadd2(h0, bc_h2(v.x)); h1 = __hadd2(h1, bc_h2(v.y));
            h2 = __hadd2(h2, bc_h2(v.z)); h3 = __hadd2(h3, bc_h2(v.w));
        }
    }
    // self-loop (once)
    {
        uint4 v = *(const uint4*)(Yp + (size_t)i * 64 + seg * 4);
        if (eg == 0) {
            h0 = __hadd2(h0, bc_h2(v.x)); h1 = __hadd2(h1, bc_h2(v.y));
            h2 = __hadd2(h2, bc_h2(v.z)); h3 = __hadd2(h3, bc_h2(v.w));
        }
    }
    // unpack to f32, reduce across the 4 edge-groups (butterfly)
    float a[8];
    { float2 f = __half22float2(h0); a[0] = f.x; a[1] = f.y; }
    { float2 f = __half22float2(h1); a[2] = f.x; a[3] = f.y; }
    { float2 f = __half22float2(h2); a[4] = f.x; a[5] = f.y; }
    { float2 f = __half22float2(h3); a[6] = f.x; a[7] = f.y; }
    #pragma unroll
    for (int m = 0; m < 8; ++m) {
        a[m] += __shfl_xor(a[m], 16, 64);
        a[m] += __shfl_xor(a[m], 32, 64);
    }
    if (eg == 0) {
        float di = dinv[i];
        uint4 o;
        o.x = pack_f16(a[0] * di, a[1] * di);
        o.y = pack_f16(a[2] * di, a[3] * di);
        o.z = pack_f16(a[4] * di, a[5] * di);
        o.w = pack_f16(a[6] * di, a[7] * di);
        *(uint4*)(Zp + (size_t)i * 64 + seg * 4) = o;
    }
}

// ---------------- O = tanh(Zp @ W2 + b2) via f16 MFMA, fused mean-pool ----------
__global__ void __launch_bounds__(256) k_mm2pool(
    const uint32* __restrict__ Zp, const float* __restrict__ W2,
    const float* __restrict__ b2, float* __restrict__ pooled) {
    int tid = threadIdx.x;
    int wid = tid >> 6, lane = tid & 63;
    int nsub = lane & 15;     // M (node) / N (feat) index within 16
    int kg = lane >> 4;       // k-group
    int fbase = wid * 32;

    // load W2 slice into registers, hi/lo fp16 split (22-bit combined mantissa)
    short8 Bh[2][4], Bl[2][4];
    #pragma unroll
    for (int c = 0; c < 2; ++c) {
        #pragma unroll
        for (int ks = 0; ks < 4; ++ks) {
            short8 h, l;
            #pragma unroll
            for (int i = 0; i < 8; ++i) {
                float w = W2[(size_t)(ks * 32 + kg * 8 + i) * H + (fbase + c * 16 + nsub)];
                __half hh = __float2half(w);
                float wl = w - __half2float(hh);
                __half hl = __float2half(wl);
                h[i] = (short)__half_as_ushort(hh);
                l[i] = (short)__half_as_ushort(hl);
            }
            Bh[c][ks] = h;
            Bl[c][ks] = l;
        }
    }
    float bb0 = b2[fbase + nsub];
    float bb1 = b2[fbase + 16 + nsub];
    float pool0 = 0.f, pool1 = 0.f;

    const int ntiles = NN / 16;          // 6250 exact
    const int stride = (int)gridDim.x;
    int t = (int)blockIdx.x;

    short8 A[4];
    if (t < ntiles) {
        const uint32* rp = Zp + (size_t)(t * 16 + nsub) * 64 + kg * 4;
        #pragma unroll
        for (int ks = 0; ks < 4; ++ks) A[ks] = *(const short8*)(rp + ks * 16);
    }
    while (t < ntiles) {
        int tn = t + stride;
        short8 An[4];
        if (tn < ntiles) {
            const uint32* rp = Zp + (size_t)(tn * 16 + nsub) * 64 + kg * 4;
            #pragma unroll
            for (int ks = 0; ks < 4; ++ks) An[ks] = *(const short8*)(rp + ks * 16);
        }
        {
            f32x4 acch0 = {0.f,0.f,0.f,0.f}, accl0 = {0.f,0.f,0.f,0.f};
            f32x4 acch1 = {0.f,0.f,0.f,0.f}, accl1 = {0.f,0.f,0.f,0.f};
            #pragma unroll
            for (int ks = 0; ks < 4; ++ks) {
                acch0 = __builtin_amdgcn_mfma_f32_16x16x32_f16(A[ks], Bh[0][ks], acch0, 0, 0, 0);
                accl0 = __builtin_amdgcn_mfma_f32_16x16x32_f16(A[ks], Bl[0][ks], accl0, 0, 0, 0);
                acch1 = __builtin_amdgcn_mfma_f32_16x16x32_f16(A[ks], Bh[1][ks], acch1, 0, 0, 0);
                accl1 = __builtin_amdgcn_mfma_f32_16x16x32_f16(A[ks], Bl[1][ks], accl1, 0, 0, 0);
            }
            #pragma unroll
            for (int r = 0; r < 4; ++r) {
                pool0 += tanhf(acch0[r] + accl0[r] + bb0);
                pool1 += tanhf(acch1[r] + accl1[r] + bb1);
            }
        }
        #pragma unroll
        for (int ks = 0; ks < 4; ++ks) A[ks] = An[ks];
        t = tn;
    }

    // reduce over the 4 kg-duplicated lanes (rows already summed into pool regs)
    pool0 += __shfl_xor(pool0, 16, 64);
    pool0 += __shfl_xor(pool0, 32, 64);
    pool1 += __shfl_xor(pool1, 16, 64);
    pool1 += __shfl_xor(pool1, 32, 64);
    if (kg == 0) {
        atomicAdd(&pooled[fbase + nsub], pool0);
        atomicAdd(&pooled[fbase + 16 + nsub], pool1);
    }
}

// ---------------- final: vel = (pooled/N) @ Wfc + bfc, mask by in_size ----------
__global__ void k_final(const float* __restrict__ pooled, const float* __restrict__ Wfc,
                        const float* __restrict__ bfc, const int* __restrict__ in_size,
                        float* __restrict__ out) {
    int t = threadIdx.x;
    if (t >= RR * OUTF) return;
    const float invn = 1.0f / (float)NN;
    float a = bfc[t];
    for (int k = 0; k < H; ++k) a += (pooled[k] * invn) * Wfc[k * (RR * OUTF) + t];
    int r = t >> 1;
    out[t] = (r < *in_size) ? a : 0.f;
}

extern "C" void kernel_launch(void* const* d_in, const int* in_sizes, int n_in,
                              void* d_out, int out_size, void* d_ws, size_t ws_size,
                              hipStream_t stream) {
    const float* x   = (const float*)d_in[0];
    const int*   ei  = (const int*)d_in[1];     // [2, E]
    const float* W1  = (const float*)d_in[3];
    const float* b1  = (const float*)d_in[4];
    const float* W2  = (const float*)d_in[5];
    const float* b2  = (const float*)d_in[6];
    const float* Wfc = (const float*)d_in[7];
    const float* bfc = (const float*)d_in[8];
    float* out = (float*)d_out;

    const int* srcp = ei;
    const int* dstp = ei + NE;

    // workspace layout (512B aligned chunks)
    char* ws = (char*)d_ws;
    size_t off = 0;
    auto alloc = [&](size_t bytes) { void* p = ws + off; off += (bytes + 511) & ~(size_t)511; return p; };
    float*  pooled  = (float*)alloc(H * 4);       // zeroed by memset below
    int*    in_size = (int*)alloc(64);            // adjacent chunk -> one memset
    int*    histG   = (int*)alloc((size_t)NBLK * NBP * 4);    // 1.2 MB
    int*    offs    = (int*)alloc((size_t)NBLK * NBP * 4);    // 1.2 MB
    int*    btot    = (int*)alloc((size_t)NB * 4);
    int*    bbase   = (int*)alloc(((size_t)NB + 1) * 4);
    uint32* data    = (uint32*)alloc((size_t)NE * 4);         // 6.4 MB exact
    float*  dinv    = (float*)alloc((size_t)NN * 4);
    float4* xd      = (float4*)alloc((size_t)NN * 16);        // x*dinv, L2-resident
    int*    csr_off = (int*)alloc((size_t)NN * 4);
    int*    csr_cnt = (int*)alloc((size_t)NN * 4);
    int*    csr_src = (int*)alloc((size_t)NE * 4);            // 6.4 MB
    float*  Axpart  = (float*)alloc((size_t)NB * ASPLIT * 512 * 4);   // 6.4 MB
    float4* Ax      = (float4*)alloc((size_t)NN * 16);
    uint32* Yp      = (uint32*)alloc((size_t)NN * 64 * 4);    // packed fp16, premult dinv
    uint32* Zp      = (uint32*)alloc((size_t)NN * 64 * 4);    // packed fp16 layer-2 agg
    (void)off; (void)ws_size; (void)in_sizes; (void)n_in; (void)out_size;

    const int nbN = (NN + 255) / 256;        // 391
    const int nbW = (NN + 3) / 4;            // 4 waves (nodes) per block

    hipMemsetAsync(pooled, 0, 1024, stream);   // pooled (512B chunk) + in_size chunk
    k_init_nodes<<<nbN, 256, 0, stream>>>(x, in_size);
    k_hist<<<NBLK, 256, 0, stream>>>(dstp, histG);
    k_btotoffs<<<(NB + 255) / 256, 256, 0, stream>>>(histG, offs, btot);
    k_bbase<<<1, 1024, 0, stream>>>(btot, bbase);
    k_scat2<<<NBLK, 256, 0, stream>>>(srcp, dstp, offs, bbase, data);
    k_build<<<NB, 256, 0, stream>>>(data, bbase, x, csr_off, csr_cnt, csr_src, dinv, xd);
    k_aggx4<<<NB * ASPLIT, 256, 0, stream>>>(data, bbase, xd, Axpart);
    k_merge<<<nbN, 256, 0, stream>>>(Axpart, xd, dinv, Ax);
    k_mm1b<<<nbW, 256, 0, stream>>>(Ax, dinv, W1, b1, Yp);
    k_aggy<<<nbW, 256, 0, stream>>>(Yp, csr_off, csr_cnt, csr_src, dinv, Zp);
    k_mm2pool<<<512, 256, 0, stream>>>(Zp, W2, b2, pooled);
    k_final<<<1, 64, 0, stream>>>(pooled, Wfc, bfc, in_size, out);
}

// Round 14
// 309.932 us; speedup vs baseline: 1.0427x; 1.0427x over previous
//
#include <hip/hip_runtime.h>
#include <hip/hip_fp16.h>

#define NN 100000
#define NE 1600000
#define INF 4
#define H 128
#define RR 20
#define OUTF 2
#define NB 782            // buckets of 128 nodes: ceil(100000/128)
#define NBP 784           // padded row stride for hist/offs matrices
#define EPB 16384         // edges per partition block
#define NBLK ((NE + EPB - 1) / EPB)   // 98
#define ASPLIT 4          // sub-blocks per bucket in layer-1 aggregation

typedef unsigned int uint32;
typedef __attribute__((ext_vector_type(8))) short short8;   // 8 f16 (4 VGPR) MFMA A/B frag
typedef __attribute__((ext_vector_type(4))) float f32x4;    // MFMA C/D frag

// pack two floats to fp16 pair (RNE): x -> low 16, y -> high 16
__device__ inline uint32 pack_f16(float x, float y) {
    return (uint32)__half_as_ushort(__float2half(x)) |
           ((uint32)__half_as_ushort(__float2half(y)) << 16);
}
__device__ inline __half2 bc_h2(uint32 u) {
    union { uint32 u; __half2 h; } c; c.u = u; return c.h;
}

// ---------------- counting-sort partition (LDS atomics only) --------------------
__global__ void __launch_bounds__(256) k_hist(const int* __restrict__ dst,
                                              int* __restrict__ histG) {
    __shared__ int h[NB];
    int b = blockIdx.x, t = threadIdx.x;
    for (int i = t; i < NB; i += 256) h[i] = 0;
    __syncthreads();
    int e0 = b * EPB, eend = min(e0 + EPB, NE);
    for (int e = e0 + t; e < eend; e += 256) atomicAdd(&h[dst[e] >> 7], 1);
    __syncthreads();
    for (int i = t; i < NB; i += 256) histG[b * NBP + i] = h[i];
}

// fused: per-bucket running offsets over partition blocks + bucket-base scan.
__global__ void __launch_bounds__(1024) k_scan(const int* __restrict__ histG,
                                               int* __restrict__ offs,
                                               int* __restrict__ bbase) {
    __shared__ int sm[1024];
    int t = threadIdx.x;
    int run = 0;
    if (t < NB) {
        for (int j = 0; j < NBLK; ++j) {
            int v = histG[j * NBP + t];
            offs[j * NBP + t] = run;
            run += v;
        }
    }
    sm[t] = (t < NB) ? run : 0;
    __syncthreads();
    for (int off = 1; off < 1024; off <<= 1) {
        int u = (t >= off) ? sm[t - off] : 0;
        __syncthreads();
        sm[t] += u;
        __syncthreads();
    }
    if (t < NB) bbase[t] = sm[t] - run;
    if (t == 0) bbase[NB] = NE;
}

__global__ void __launch_bounds__(256) k_scat2(const int* __restrict__ src,
                                               const int* __restrict__ dst,
                                               const int* __restrict__ offs,
                                               const int* __restrict__ bbase,
                                               uint32* __restrict__ data) {
    __shared__ int cur[NB];
    int b = blockIdx.x, t = threadIdx.x;
    for (int i = t; i < NB; i += 256) cur[i] = offs[b * NBP + i] + bbase[i];
    __syncthreads();
    int e0 = b * EPB, eend = min(e0 + EPB, NE);
    for (int e = e0 + t; e < eend; e += 256) {
        int s = src[e], d = dst[e];
        int p = atomicAdd(&cur[d >> 7], 1);
        data[p] = ((uint32)s << 7) | (uint32)(d & 127);
    }
}

// one block per bucket: histogram -> csr_off/csr_cnt/dinv/xd + node-sorted csr_src
// + in_size ballot (x row is already loaded here for xd).
__global__ void __launch_bounds__(256) k_build(const uint32* __restrict__ data,
                                               const int* __restrict__ bbase,
                                               const float* __restrict__ x,
                                               int* __restrict__ csr_off,
                                               int* __restrict__ csr_cnt,
                                               int* __restrict__ csr_src,
                                               float* __restrict__ dinv,
                                               float4* __restrict__ xd,
                                               int* __restrict__ in_size) {
    __shared__ int hist[128], pfx[128], curs[128];
    int bkt = blockIdx.x;
    int t = threadIdx.x;
    int rbeg = bbase[bkt], rend = bbase[bkt + 1];
    if (t < 128) hist[t] = 0;
    __syncthreads();
    for (int j = rbeg + t; j < rend; j += 256)
        atomicAdd(&hist[data[j] & 127], 1);
    __syncthreads();
    if (t < 128) pfx[t] = hist[t];
    __syncthreads();
    for (int off = 1; off < 128; off <<= 1) {
        int u = (t < 128 && t >= off) ? pfx[t - off] : 0;
        __syncthreads();
        if (t < 128) pfx[t] += u;
        __syncthreads();
    }
    int nodeCount = min(128, NN - bkt * 128);
    bool pred = false;
    if (t < nodeCount) {
        int gi = bkt * 128 + t;
        int excl = rbeg + pfx[t] - hist[t];
        csr_off[gi] = excl;
        csr_cnt[gi] = hist[t];
        curs[t] = excl;
        float di = rsqrtf((float)(hist[t] + 1));
        dinv[gi] = di;
        const float4 xv = *(const float4*)(x + (size_t)gi * INF);
        xd[gi] = make_float4(xv.x * di, xv.y * di, xv.z * di, xv.w * di);
        pred = (xv.x != 0.f) && (xv.y != 0.f);
    }
    unsigned long long m = __ballot(pred);
    if ((t & 63) == 0) {
        int c = __popcll(m);
        if (c) atomicAdd(in_size, c);
    }
    __syncthreads();
    for (int j = rbeg + t; j < rend; j += 256) {
        uint32 r = data[j];
        int p = atomicAdd(&curs[r & 127], 1);
        csr_src[p] = (int)(r >> 7);
    }
}

// ---------------- layer-1 aggregation: 4 blocks per bucket, no atomics ----------
__global__ void __launch_bounds__(256) k_aggx4(const uint32* __restrict__ data,
                                               const int* __restrict__ bbase,
                                               const float4* __restrict__ xd,
                                               float* __restrict__ Axpart) {
    __shared__ float acc[128][4];
    int bkt = blockIdx.x >> 2, sp = blockIdx.x & 3;
    int t = threadIdx.x;
    if (t < 128) { acc[t][0] = 0.f; acc[t][1] = 0.f; acc[t][2] = 0.f; acc[t][3] = 0.f; }
    int rbeg = bbase[bkt], rend = bbase[bkt + 1];
    int len = rend - rbeg;
    int q0 = rbeg + ((long long)len * sp >> 2);
    int q1 = rbeg + ((long long)len * (sp + 1) >> 2);
    __syncthreads();
    for (int j = q0 + t; j < q1; j += 256) {
        uint32 r = data[j];
        int s = (int)(r >> 7), dl = (int)(r & 127);
        const float4 v = xd[s];
        atomicAdd(&acc[dl][0], v.x);
        atomicAdd(&acc[dl][1], v.y);
        atomicAdd(&acc[dl][2], v.z);
        atomicAdd(&acc[dl][3], v.w);
    }
    __syncthreads();
    float* dstp = Axpart + (size_t)blockIdx.x * 512;
    for (int i = t; i < 512; i += 256) dstp[i] = ((const float*)acc)[i];
}

// fused merge + matvec + tanh + fp16 pack, one block per bucket:
// phase 1: 128 threads merge parts+self -> LDS; phase 2: 8192 outputs -> Yp.
__global__ void __launch_bounds__(256) k_mm1c(const float* __restrict__ Axpart,
                                              const float4* __restrict__ xd,
                                              const float* __restrict__ dinv,
                                              const float* __restrict__ W1,
                                              const float* __restrict__ b1,
                                              uint32* __restrict__ Yp) {
    __shared__ float axs[128][4];
    __shared__ float ds[128];
    __shared__ float w1s[4][128];
    __shared__ float b1s[128];
    int bkt = blockIdx.x;
    int t = threadIdx.x;
    if (t < 128) b1s[t] = b1[t];
    ((float*)w1s)[t] = W1[t];
    ((float*)w1s)[256 + t] = W1[256 + t];
    int nodeCount = min(128, NN - bkt * 128);
    if (t < nodeCount) {
        int gi = bkt * 128 + t;
        float4 a = xd[gi];   // self-loop term
        #pragma unroll
        for (int sp = 0; sp < 4; ++sp) {
            const float4 p = *(const float4*)(Axpart + ((size_t)(bkt * 4 + sp)) * 512 + t * 4);
            a.x += p.x; a.y += p.y; a.z += p.z; a.w += p.w;
        }
        float di = dinv[gi];
        axs[t][0] = a.x * di; axs[t][1] = a.y * di;
        axs[t][2] = a.z * di; axs[t][3] = a.w * di;
        ds[t] = di;
    }
    __syncthreads();
    int nbase = bkt * 128;
    #pragma unroll
    for (int rep = 0; rep < 32; ++rep) {
        int flat = rep * 256 + t;       // 8192 = 128 nodes * 64 uint outputs
        int node = flat >> 6;
        int fp = flat & 63;
        int gi = nbase + node;
        if (gi < NN) {
            float a0 = axs[node][0], a1 = axs[node][1];
            float a2 = axs[node][2], a3 = axs[node][3];
            float di = ds[node];
            int f0 = fp * 2;
            float d0 = b1s[f0]     + a0 * w1s[0][f0]     + a1 * w1s[1][f0]
                                   + a2 * w1s[2][f0]     + a3 * w1s[3][f0];
            float d1 = b1s[f0 + 1] + a0 * w1s[0][f0 + 1] + a1 * w1s[1][f0 + 1]
                                   + a2 * w1s[2][f0 + 1] + a3 * w1s[3][f0 + 1];
            Yp[(size_t)gi * 64 + fp] = pack_f16(tanhf(d0) * di, tanhf(d1) * di);
        }
    }
}

// ---------------- layer 2 gather: Zp = f16( dinv[i]*(sum Yp[s] + Yp[i]) ) -------
// one wave per node; lane = (edge-group eg, 16B segment seg); unroll x4.
// Register accumulation at the random-256B fabric ceiling (~3.5 TB/s, R12/R13).
__global__ void k_aggy(const uint32* __restrict__ Yp, const int* __restrict__ csr_off,
                       const int* __restrict__ csr_cnt, const int* __restrict__ csr_src,
                       const float* __restrict__ dinv, uint32* __restrict__ Zp) {
    int wid = threadIdx.x >> 6;
    int lane = threadIdx.x & 63;
    int i = blockIdx.x * 4 + wid;
    if (i >= NN) return;
    int b = csr_off[i];
    int n = csr_cnt[i];
    int eg = lane >> 4, seg = lane & 15;

    __half2 h0 = bc_h2(0u), h1 = bc_h2(0u), h2 = bc_h2(0u), h3 = bc_h2(0u);
    int j = 0;
    for (; j + 16 <= n; j += 16) {
        int s0 = csr_src[b + j + eg];
        int s1 = csr_src[b + j + 4 + eg];
        int s2 = csr_src[b + j + 8 + eg];
        int s3 = csr_src[b + j + 12 + eg];
        uint4 v0 = *(const uint4*)(Yp + (size_t)s0 * 64 + seg * 4);
        uint4 v1 = *(const uint4*)(Yp + (size_t)s1 * 64 + seg * 4);
        uint4 v2 = *(const uint4*)(Yp + (size_t)s2 * 64 + seg * 4);
        uint4 v3 = *(const uint4*)(Yp + (size_t)s3 * 64 + seg * 4);
        h0 = __hadd2(h0, bc_h2(v0.x)); h1 = __hadd2(h1, bc_h2(v0.y));
        h2 = __hadd2(h2, bc_h2(v0.z)); h3 = __hadd2(h3, bc_h2(v0.w));
        h0 = __hadd2(h0, bc_h2(v1.x)); h1 = __hadd2(h1, bc_h2(v1.y));
        h2 = __hadd2(h2, bc_h2(v1.z)); h3 = __hadd2(h3, bc_h2(v1.w));
        h0 = __hadd2(h0, bc_h2(v2.x)); h1 = __hadd2(h1, bc_h2(v2.y));
        h2 = __hadd2(h2, bc_h2(v2.z)); h3 = __hadd2(h3, bc_h2(v2.w));
        h0 = __hadd2(h0, bc_h2(v3.x)); h1 = __hadd2(h1, bc_h2(v3.y));
        h2 = __hadd2(h2, bc_h2(v3.z)); h3 = __hadd2(h3, bc_h2(v3.w));
    }
    for (; j + 8 <= n; j += 8) {
        int s0 = csr_src[b + j + eg];
        int s1 = csr_src[b + j + 4 + eg];
        uint4 v0 = *(const uint4*)(Yp + (size_t)s0 * 64 + seg * 4);
        uint4 v1 = *(const uint4*)(Yp + (size_t)s1 * 64 + seg * 4);
        h0 = __hadd2(h0, bc_h2(v0.x)); h1 = __hadd2(h1, bc_h2(v0.y));
        h2 = __hadd2(h2, bc_h2(v0.z)); h3 = __hadd2(h3, bc_h2(v0.w));
        h0 = __hadd2(h0, bc_h2(v1.x)); h1 = __hadd2(h1, bc_h2(v1.y));
        h2 = __hadd2(h2, bc_h2(v1.z)); h3 = __hadd2(h3, bc_h2(v1.w));
    }
    for (; j < n; j += 4) {
        int jj = j + eg;
        bool valid = jj < n;
        int s = valid ? csr_src[b + jj] : i;   // safe address; contribution masked
        uint4 v = *(const uint4*)(Yp + (size_t)s * 64 + seg * 4);
        if (valid) {
            h0 = __hadd2(h0, bc_h2(v.x)); h1 = __hadd2(h1, bc_h2(v.y));
            h2 = __hadd2(h2, bc_h2(v.z)); h3 = __hadd2(h3, bc_h2(v.w));
        }
    }
    // self-loop (once)
    {
        uint4 v = *(const uint4*)(Yp + (size_t)i * 64 + seg * 4);
        if (eg == 0) {
            h0 = __hadd2(h0, bc_h2(v.x)); h1 = __hadd2(h1, bc_h2(v.y));
            h2 = __hadd2(h2, bc_h2(v.z)); h3 = __hadd2(h3, bc_h2(v.w));
        }
    }
    // unpack to f32, reduce across the 4 edge-groups (butterfly)
    float a[8];
    { float2 f = __half22float2(h0); a[0] = f.x; a[1] = f.y; }
    { float2 f = __half22float2(h1); a[2] = f.x; a[3] = f.y; }
    { float2 f = __half22float2(h2); a[4] = f.x; a[5] = f.y; }
    { float2 f = __half22float2(h3); a[6] = f.x; a[7] = f.y; }
    #pragma unroll
    for (int m = 0; m < 8; ++m) {
        a[m] += __shfl_xor(a[m], 16, 64);
        a[m] += __shfl_xor(a[m], 32, 64);
    }
    if (eg == 0) {
        float di = dinv[i];
        uint4 o;
        o.x = pack_f16(a[0] * di, a[1] * di);
        o.y = pack_f16(a[2] * di, a[3] * di);
        o.z = pack_f16(a[4] * di, a[5] * di);
        o.w = pack_f16(a[6] * di, a[7] * di);
        *(uint4*)(Zp + (size_t)i * 64 + seg * 4) = o;
    }
}

// ---------------- O = tanh(Zp @ W2 + b2) via f16 MFMA, fused mean-pool ----------
__global__ void __launch_bounds__(256) k_mm2pool(
    const uint32* __restrict__ Zp, const float* __restrict__ W2,
    const float* __restrict__ b2, float* __restrict__ pooled) {
    int tid = threadIdx.x;
    int wid = tid >> 6, lane = tid & 63;
    int nsub = lane & 15;     // M (node) / N (feat) index within 16
    int kg = lane >> 4;       // k-group
    int fbase = wid * 32;

    // load W2 slice into registers, hi/lo fp16 split (22-bit combined mantissa)
    short8 Bh[2][4], Bl[2][4];
    #pragma unroll
    for (int c = 0; c < 2; ++c) {
        #pragma unroll
        for (int ks = 0; ks < 4; ++ks) {
            short8 h, l;
            #pragma unroll
            for (int i = 0; i < 8; ++i) {
                float w = W2[(size_t)(ks * 32 + kg * 8 + i) * H + (fbase + c * 16 + nsub)];
                __half hh = __float2half(w);
                float wl = w - __half2float(hh);
                __half hl = __float2half(wl);
                h[i] = (short)__half_as_ushort(hh);
                l[i] = (short)__half_as_ushort(hl);
            }
            Bh[c][ks] = h;
            Bl[c][ks] = l;
        }
    }
    float bb0 = b2[fbase + nsub];
    float bb1 = b2[fbase + 16 + nsub];
    float pool0 = 0.f, pool1 = 0.f;

    const int ntiles = NN / 16;          // 6250 exact
    const int stride = (int)gridDim.x;
    int t = (int)blockIdx.x;

    short8 A[4];
    if (t < ntiles) {
        const uint32* rp = Zp + (size_t)(t * 16 + nsub) * 64 + kg * 4;
        #pragma unroll
        for (int ks = 0; ks < 4; ++ks) A[ks] = *(const short8*)(rp + ks * 16);
    }
    while (t < ntiles) {
        int tn = t + stride;
        short8 An[4];
        if (tn < ntiles) {
            const uint32* rp = Zp + (size_t)(tn * 16 + nsub) * 64 + kg * 4;
            #pragma unroll
            for (int ks = 0; ks < 4; ++ks) An[ks] = *(const short8*)(rp + ks * 16);
        }
        {
            f32x4 acch0 = {0.f,0.f,0.f,0.f}, accl0 = {0.f,0.f,0.f,0.f};
            f32x4 acch1 = {0.f,0.f,0.f,0.f}, accl1 = {0.f,0.f,0.f,0.f};
            #pragma unroll
            for (int ks = 0; ks < 4; ++ks) {
                acch0 = __builtin_amdgcn_mfma_f32_16x16x32_f16(A[ks], Bh[0][ks], acch0, 0, 0, 0);
                accl0 = __builtin_amdgcn_mfma_f32_16x16x32_f16(A[ks], Bl[0][ks], accl0, 0, 0, 0);
                acch1 = __builtin_amdgcn_mfma_f32_16x16x32_f16(A[ks], Bh[1][ks], acch1, 0, 0, 0);
                accl1 = __builtin_amdgcn_mfma_f32_16x16x32_f16(A[ks], Bl[1][ks], accl1, 0, 0, 0);
            }
            #pragma unroll
            for (int r = 0; r < 4; ++r) {
                pool0 += tanhf(acch0[r] + accl0[r] + bb0);
                pool1 += tanhf(acch1[r] + accl1[r] + bb1);
            }
        }
        #pragma unroll
        for (int ks = 0; ks < 4; ++ks) A[ks] = An[ks];
        t = tn;
    }

    // reduce over the 4 kg-duplicated lanes (rows already summed into pool regs)
    pool0 += __shfl_xor(pool0, 16, 64);
    pool0 += __shfl_xor(pool0, 32, 64);
    pool1 += __shfl_xor(pool1, 16, 64);
    pool1 += __shfl_xor(pool1, 32, 64);
    if (kg == 0) {
        atomicAdd(&pooled[fbase + nsub], pool0);
        atomicAdd(&pooled[fbase + 16 + nsub], pool1);
    }
}

// ---------------- final: vel = (pooled/N) @ Wfc + bfc, mask by in_size ----------
__global__ void k_final(const float* __restrict__ pooled, const float* __restrict__ Wfc,
                        const float* __restrict__ bfc, const int* __restrict__ in_size,
                        float* __restrict__ out) {
    int t = threadIdx.x;
    if (t >= RR * OUTF) return;
    const float invn = 1.0f / (float)NN;
    float a = bfc[t];
    for (int k = 0; k < H; ++k) a += (pooled[k] * invn) * Wfc[k * (RR * OUTF) + t];
    int r = t >> 1;
    out[t] = (r < *in_size) ? a : 0.f;
}

extern "C" void kernel_launch(void* const* d_in, const int* in_sizes, int n_in,
                              void* d_out, int out_size, void* d_ws, size_t ws_size,
                              hipStream_t stream) {
    const float* x   = (const float*)d_in[0];
    const int*   ei  = (const int*)d_in[1];     // [2, E]
    const float* W1  = (const float*)d_in[3];
    const float* b1  = (const float*)d_in[4];
    const float* W2  = (const float*)d_in[5];
    const float* b2  = (const float*)d_in[6];
    const float* Wfc = (const float*)d_in[7];
    const float* bfc = (const float*)d_in[8];
    float* out = (float*)d_out;

    const int* srcp = ei;
    const int* dstp = ei + NE;

    // workspace layout (512B aligned chunks)
    char* ws = (char*)d_ws;
    size_t off = 0;
    auto alloc = [&](size_t bytes) { void* p = ws + off; off += (bytes + 511) & ~(size_t)511; return p; };
    float*  pooled  = (float*)alloc(H * 4);       // zeroed by memset below
    int*    in_size = (int*)alloc(64);            // adjacent chunk -> one memset
    int*    histG   = (int*)alloc((size_t)NBLK * NBP * 4);    // 307 KB
    int*    offs    = (int*)alloc((size_t)NBLK * NBP * 4);    // 307 KB
    int*    bbase   = (int*)alloc(((size_t)NB + 1) * 4);
    uint32* data    = (uint32*)alloc((size_t)NE * 4);         // 6.4 MB exact
    float*  dinv    = (float*)alloc((size_t)NN * 4);
    float4* xd      = (float4*)alloc((size_t)NN * 16);        // x*dinv, L2-resident
    int*    csr_off = (int*)alloc((size_t)NN * 4);
    int*    csr_cnt = (int*)alloc((size_t)NN * 4);
    int*    csr_src = (int*)alloc((size_t)NE * 4);            // 6.4 MB
    float*  Axpart  = (float*)alloc((size_t)NB * ASPLIT * 512 * 4);   // 6.4 MB
    uint32* Yp      = (uint32*)alloc((size_t)NN * 64 * 4);    // packed fp16, premult dinv
    uint32* Zp      = (uint32*)alloc((size_t)NN * 64 * 4);    // packed fp16 layer-2 agg
    (void)off; (void)ws_size; (void)in_sizes; (void)n_in; (void)out_size;

    const int nbW = (NN + 3) / 4;            // 4 waves (nodes) per block

    hipMemsetAsync(pooled, 0, 1024, stream);   // pooled (512B chunk) + in_size chunk
    k_hist<<<NBLK, 256, 0, stream>>>(dstp, histG);
    k_scan<<<1, 1024, 0, stream>>>(histG, offs, bbase);
    k_scat2<<<NBLK, 256, 0, stream>>>(srcp, dstp, offs, bbase, data);
    k_build<<<NB, 256, 0, stream>>>(data, bbase, x, csr_off, csr_cnt, csr_src, dinv, xd, in_size);
    k_aggx4<<<NB * ASPLIT, 256, 0, stream>>>(data, bbase, xd, Axpart);
    k_mm1c<<<NB, 256, 0, stream>>>(Axpart, xd, dinv, W1, b1, Yp);
    k_aggy<<<nbW, 256, 0, stream>>>(Yp, csr_off, csr_cnt, csr_src, dinv, Zp);
    k_mm2pool<<<512, 256, 0, stream>>>(Zp, W2, b2, pooled);
    k_final<<<1, 64, 0, stream>>>(pooled, Wfc, bfc, in_size, out);
}

// Round 16
// 277.558 us; speedup vs baseline: 1.1643x; 1.1166x over previous
//
#include <hip/hip_runtime.h>
#include <hip/hip_fp16.h>

#define NN 100000
#define NE 1600000
#define INF 4
#define H 128
#define RR 20
#define OUTF 2
#define NB 782            // buckets of 128 nodes: ceil(100000/128)
#define NBP 784           // padded row stride for hist/offs matrices
#define EPB 16384         // edges per partition block
#define NBLK ((NE + EPB - 1) / EPB)   // 98

typedef unsigned int uint32;
typedef __attribute__((ext_vector_type(8))) short short8;   // 8 f16 (4 VGPR) MFMA A/B frag
typedef __attribute__((ext_vector_type(4))) float f32x4;    // MFMA C/D frag

// pack two floats to fp16 pair (RNE): x -> low 16, y -> high 16
__device__ inline uint32 pack_f16(float x, float y) {
    return (uint32)__half_as_ushort(__float2half(x)) |
           ((uint32)__half_as_ushort(__float2half(y)) << 16);
}
__device__ inline __half2 bc_h2(uint32 u) {
    union { uint32 u; __half2 h; } c; c.u = u; return c.h;
}

// ---------------- counting-sort partition (LDS atomics only) --------------------
__global__ void __launch_bounds__(256) k_hist(const int* __restrict__ dst,
                                              int* __restrict__ histG) {
    __shared__ int h[NB];
    int b = blockIdx.x, t = threadIdx.x;
    for (int i = t; i < NB; i += 256) h[i] = 0;
    __syncthreads();
    int e0 = b * EPB, eend = min(e0 + EPB, NE);
    for (int e = e0 + t; e < eend; e += 256) atomicAdd(&h[dst[e] >> 7], 1);
    __syncthreads();
    for (int i = t; i < NB; i += 256) histG[b * NBP + i] = h[i];
}

// fused: per-bucket running offsets over partition blocks + bucket-base scan.
__global__ void __launch_bounds__(1024) k_scan(const int* __restrict__ histG,
                                               int* __restrict__ offs,
                                               int* __restrict__ bbase) {
    __shared__ int sm[1024];
    int t = threadIdx.x;
    int run = 0;
    if (t < NB) {
        for (int j = 0; j < NBLK; ++j) {
            int v = histG[j * NBP + t];
            offs[j * NBP + t] = run;
            run += v;
        }
    }
    sm[t] = (t < NB) ? run : 0;
    __syncthreads();
    for (int off = 1; off < 1024; off <<= 1) {
        int u = (t >= off) ? sm[t - off] : 0;
        __syncthreads();
        sm[t] += u;
        __syncthreads();
    }
    if (t < NB) bbase[t] = sm[t] - run;
    if (t == 0) bbase[NB] = NE;
}

__global__ void __launch_bounds__(256) k_scat2(const int* __restrict__ src,
                                               const int* __restrict__ dst,
                                               const int* __restrict__ offs,
                                               const int* __restrict__ bbase,
                                               uint32* __restrict__ data) {
    __shared__ int cur[NB];
    int b = blockIdx.x, t = threadIdx.x;
    for (int i = t; i < NB; i += 256) cur[i] = offs[b * NBP + i] + bbase[i];
    __syncthreads();
    int e0 = b * EPB, eend = min(e0 + EPB, NE);
    for (int e = e0 + t; e < eend; e += 256) {
        int s = src[e], d = dst[e];
        int p = atomicAdd(&cur[d >> 7], 1);
        data[p] = ((uint32)s << 7) | (uint32)(d & 127);
    }
}

// one block per bucket: histogram -> csr_off/csr_cnt/dinv/xd + node-sorted csr_src
// + in_size ballot (x row is already loaded here for xd).
__global__ void __launch_bounds__(256) k_build(const uint32* __restrict__ data,
                                               const int* __restrict__ bbase,
                                               const float* __restrict__ x,
                                               int* __restrict__ csr_off,
                                               int* __restrict__ csr_cnt,
                                               int* __restrict__ csr_src,
                                               float* __restrict__ dinv,
                                               float4* __restrict__ xd,
                                               int* __restrict__ in_size) {
    __shared__ int hist[128], pfx[128], curs[128];
    int bkt = blockIdx.x;
    int t = threadIdx.x;
    int rbeg = bbase[bkt], rend = bbase[bkt + 1];
    if (t < 128) hist[t] = 0;
    __syncthreads();
    for (int j = rbeg + t; j < rend; j += 256)
        atomicAdd(&hist[data[j] & 127], 1);
    __syncthreads();
    if (t < 128) pfx[t] = hist[t];
    __syncthreads();
    for (int off = 1; off < 128; off <<= 1) {
        int u = (t < 128 && t >= off) ? pfx[t - off] : 0;
        __syncthreads();
        if (t < 128) pfx[t] += u;
        __syncthreads();
    }
    int nodeCount = min(128, NN - bkt * 128);
    bool pred = false;
    if (t < nodeCount) {
        int gi = bkt * 128 + t;
        int excl = rbeg + pfx[t] - hist[t];
        csr_off[gi] = excl;
        csr_cnt[gi] = hist[t];
        curs[t] = excl;
        float di = rsqrtf((float)(hist[t] + 1));
        dinv[gi] = di;
        const float4 xv = *(const float4*)(x + (size_t)gi * INF);
        xd[gi] = make_float4(xv.x * di, xv.y * di, xv.z * di, xv.w * di);
        pred = (xv.x != 0.f) && (xv.y != 0.f);
    }
    unsigned long long m = __ballot(pred);
    if ((t & 63) == 0) {
        int c = __popcll(m);
        if (c) atomicAdd(in_size, c);
    }
    __syncthreads();
    for (int j = rbeg + t; j < rend; j += 256) {
        uint32 r = data[j];
        int p = atomicAdd(&curs[r & 127], 1);
        csr_src[p] = (int)(r >> 7);
    }
}

// ---------------- fused layer 1: CSR gather-reduce + matvec + tanh + pack -------
// One 16-lane group per node (atomic-free): lanes gather xd[csr_src[...]] (L2),
// butterfly-reduce over the group, add self-term, then the same lanes compute the
// 4->128 matvec + tanh + fp16 pack in-register and store the 256B Yp row.
__global__ void __launch_bounds__(256) k_l1(const int* __restrict__ csr_off,
                                            const int* __restrict__ csr_cnt,
                                            const int* __restrict__ csr_src,
                                            const float4* __restrict__ xd,
                                            const float* __restrict__ dinv,
                                            const float* __restrict__ W1,
                                            const float* __restrict__ b1,
                                            uint32* __restrict__ Yp) {
    __shared__ float w1s[4][128];
    __shared__ float b1s[128];
    int t = threadIdx.x;
    if (t < 128) b1s[t] = b1[t];
    ((float*)w1s)[t] = W1[t];
    ((float*)w1s)[256 + t] = W1[256 + t];
    __syncthreads();
    int wid = t >> 6, lane = t & 63;
    int l16 = lane & 15, grp = lane >> 4;
    int i = blockIdx.x * 16 + wid * 4 + grp;      // NN = 6250*16 exact
    int b = csr_off[i], n = csr_cnt[i];
    float a0 = 0.f, a1 = 0.f, a2 = 0.f, a3 = 0.f;
    for (int j = l16; j < n; j += 16) {
        int s = csr_src[b + j];
        const float4 v = xd[s];
        a0 += v.x; a1 += v.y; a2 += v.z; a3 += v.w;
    }
    #pragma unroll
    for (int off = 1; off < 16; off <<= 1) {
        a0 += __shfl_xor(a0, off, 64);
        a1 += __shfl_xor(a1, off, 64);
        a2 += __shfl_xor(a2, off, 64);
        a3 += __shfl_xor(a3, off, 64);
    }
    const float4 self = xd[i];
    float di = dinv[i];
    a0 = (a0 + self.x) * di;
    a1 = (a1 + self.y) * di;
    a2 = (a2 + self.z) * di;
    a3 = (a3 + self.w) * di;
    int f0 = l16 * 8;
    uint4 o;
    #pragma unroll
    for (int q = 0; q < 4; ++q) {
        int f = f0 + q * 2;
        float d0 = b1s[f]     + a0 * w1s[0][f]     + a1 * w1s[1][f]
                              + a2 * w1s[2][f]     + a3 * w1s[3][f];
        float d1 = b1s[f + 1] + a0 * w1s[0][f + 1] + a1 * w1s[1][f + 1]
                              + a2 * w1s[2][f + 1] + a3 * w1s[3][f + 1];
        (&o.x)[q] = pack_f16(tanhf(d0) * di, tanhf(d1) * di);
    }
    *(uint4*)(Yp + (size_t)i * 64 + l16 * 4) = o;
}

// ---------------- layer 2 gather: Zp = f16( dinv[i]*(sum Yp[s] + Yp[i]) ) -------
// one wave per node; lane = (edge-group eg, 16B segment seg); unroll x4.
// Register accumulation at the random-256B fabric ceiling (~3.5 TB/s, R12/R13).
__global__ void k_aggy(const uint32* __restrict__ Yp, const int* __restrict__ csr_off,
                       const int* __restrict__ csr_cnt, const int* __restrict__ csr_src,
                       const float* __restrict__ dinv, uint32* __restrict__ Zp) {
    int wid = threadIdx.x >> 6;
    int lane = threadIdx.x & 63;
    int i = blockIdx.x * 4 + wid;
    if (i >= NN) return;
    int b = csr_off[i];
    int n = csr_cnt[i];
    int eg = lane >> 4, seg = lane & 15;

    __half2 h0 = bc_h2(0u), h1 = bc_h2(0u), h2 = bc_h2(0u), h3 = bc_h2(0u);
    int j = 0;
    for (; j + 16 <= n; j += 16) {
        int s0 = csr_src[b + j + eg];
        int s1 = csr_src[b + j + 4 + eg];
        int s2 = csr_src[b + j + 8 + eg];
        int s3 = csr_src[b + j + 12 + eg];
        uint4 v0 = *(const uint4*)(Yp + (size_t)s0 * 64 + seg * 4);
        uint4 v1 = *(const uint4*)(Yp + (size_t)s1 * 64 + seg * 4);
        uint4 v2 = *(const uint4*)(Yp + (size_t)s2 * 64 + seg * 4);
        uint4 v3 = *(const uint4*)(Yp + (size_t)s3 * 64 + seg * 4);
        h0 = __hadd2(h0, bc_h2(v0.x)); h1 = __hadd2(h1, bc_h2(v0.y));
        h2 = __hadd2(h2, bc_h2(v0.z)); h3 = __hadd2(h3, bc_h2(v0.w));
        h0 = __hadd2(h0, bc_h2(v1.x)); h1 = __hadd2(h1, bc_h2(v1.y));
        h2 = __hadd2(h2, bc_h2(v1.z)); h3 = __hadd2(h3, bc_h2(v1.w));
        h0 = __hadd2(h0, bc_h2(v2.x)); h1 = __hadd2(h1, bc_h2(v2.y));
        h2 = __hadd2(h2, bc_h2(v2.z)); h3 = __hadd2(h3, bc_h2(v2.w));
        h0 = __hadd2(h0, bc_h2(v3.x)); h1 = __hadd2(h1, bc_h2(v3.y));
        h2 = __hadd2(h2, bc_h2(v3.z)); h3 = __hadd2(h3, bc_h2(v3.w));
    }
    for (; j + 8 <= n; j += 8) {
        int s0 = csr_src[b + j + eg];
        int s1 = csr_src[b + j + 4 + eg];
        uint4 v0 = *(const uint4*)(Yp + (size_t)s0 * 64 + seg * 4);
        uint4 v1 = *(const uint4*)(Yp + (size_t)s1 * 64 + seg * 4);
        h0 = __hadd2(h0, bc_h2(v0.x)); h1 = __hadd2(h1, bc_h2(v0.y));
        h2 = __hadd2(h2, bc_h2(v0.z)); h3 = __hadd2(h3, bc_h2(v0.w));
        h0 = __hadd2(h0, bc_h2(v1.x)); h1 = __hadd2(h1, bc_h2(v1.y));
        h2 = __hadd2(h2, bc_h2(v1.z)); h3 = __hadd2(h3, bc_h2(v1.w));
    }
    for (; j < n; j += 4) {
        int jj = j + eg;
        bool valid = jj < n;
        int s = valid ? csr_src[b + jj] : i;   // safe address; contribution masked
        uint4 v = *(const uint4*)(Yp + (size_t)s * 64 + seg * 4);
        if (valid) {
            h0 = __hadd2(h0, bc_h2(v.x)); h1 = __hadd2(h1, bc_h2(v.y));
            h2 = __hadd2(h2, bc_h2(v.z)); h3 = __hadd2(h3, bc_h2(v.w));
        }
    }
    // self-loop (once)
    {
        uint4 v = *(const uint4*)(Yp + (size_t)i * 64 + seg * 4);
        if (eg == 0) {
            h0 = __hadd2(h0, bc_h2(v.x)); h1 = __hadd2(h1, bc_h2(v.y));
            h2 = __hadd2(h2, bc_h2(v.z)); h3 = __hadd2(h3, bc_h2(v.w));
        }
    }
    // unpack to f32, reduce across the 4 edge-groups (butterfly)
    float a[8];
    { float2 f = __half22float2(h0); a[0] = f.x; a[1] = f.y; }
    { float2 f = __half22float2(h1); a[2] = f.x; a[3] = f.y; }
    { float2 f = __half22float2(h2); a[4] = f.x; a[5] = f.y; }
    { float2 f = __half22float2(h3); a[6] = f.x; a[7] = f.y; }
    #pragma unroll
    for (int m = 0; m < 8; ++m) {
        a[m] += __shfl_xor(a[m], 16, 64);
        a[m] += __shfl_xor(a[m], 32, 64);
    }
    if (eg == 0) {
        float di = dinv[i];
        uint4 o;
        o.x = pack_f16(a[0] * di, a[1] * di);
        o.y = pack_f16(a[2] * di, a[3] * di);
        o.z = pack_f16(a[4] * di, a[5] * di);
        o.w = pack_f16(a[6] * di, a[7] * di);
        *(uint4*)(Zp + (size_t)i * 64 + seg * 4) = o;
    }
}

// ---------------- O = tanh(Zp @ W2 + b2) via f16 MFMA, fused mean-pool ----------
__global__ void __launch_bounds__(256) k_mm2pool(
    const uint32* __restrict__ Zp, const float* __restrict__ W2,
    const float* __restrict__ b2, float* __restrict__ pooled) {
    int tid = threadIdx.x;
    int wid = tid >> 6, lane = tid & 63;
    int nsub = lane & 15;     // M (node) / N (feat) index within 16
    int kg = lane >> 4;       // k-group
    int fbase = wid * 32;

    // load W2 slice into registers, hi/lo fp16 split (22-bit combined mantissa)
    short8 Bh[2][4], Bl[2][4];
    #pragma unroll
    for (int c = 0; c < 2; ++c) {
        #pragma unroll
        for (int ks = 0; ks < 4; ++ks) {
            short8 h, l;
            #pragma unroll
            for (int i = 0; i < 8; ++i) {
                float w = W2[(size_t)(ks * 32 + kg * 8 + i) * H + (fbase + c * 16 + nsub)];
                __half hh = __float2half(w);
                float wl = w - __half2float(hh);
                __half hl = __float2half(wl);
                h[i] = (short)__half_as_ushort(hh);
                l[i] = (short)__half_as_ushort(hl);
            }
            Bh[c][ks] = h;
            Bl[c][ks] = l;
        }
    }
    float bb0 = b2[fbase + nsub];
    float bb1 = b2[fbase + 16 + nsub];
    float pool0 = 0.f, pool1 = 0.f;

    const int ntiles = NN / 16;          // 6250 exact
    const int stride = (int)gridDim.x;
    int t = (int)blockIdx.x;

    short8 A[4];
    if (t < ntiles) {
        const uint32* rp = Zp + (size_t)(t * 16 + nsub) * 64 + kg * 4;
        #pragma unroll
        for (int ks = 0; ks < 4; ++ks) A[ks] = *(const short8*)(rp + ks * 16);
    }
    while (t < ntiles) {
        int tn = t + stride;
        short8 An[4];
        if (tn < ntiles) {
            const uint32* rp = Zp + (size_t)(tn * 16 + nsub) * 64 + kg * 4;
            #pragma unroll
            for (int ks = 0; ks < 4; ++ks) An[ks] = *(const short8*)(rp + ks * 16);
        }
        {
            f32x4 acch0 = {0.f,0.f,0.f,0.f}, accl0 = {0.f,0.f,0.f,0.f};
            f32x4 acch1 = {0.f,0.f,0.f,0.f}, accl1 = {0.f,0.f,0.f,0.f};
            #pragma unroll
            for (int ks = 0; ks < 4; ++ks) {
                acch0 = __builtin_amdgcn_mfma_f32_16x16x32_f16(A[ks], Bh[0][ks], acch0, 0, 0, 0);
                accl0 = __builtin_amdgcn_mfma_f32_16x16x32_f16(A[ks], Bl[0][ks], accl0, 0, 0, 0);
                acch1 = __builtin_amdgcn_mfma_f32_16x16x32_f16(A[ks], Bh[1][ks], acch1, 0, 0, 0);
                accl1 = __builtin_amdgcn_mfma_f32_16x16x32_f16(A[ks], Bl[1][ks], accl1, 0, 0, 0);
            }
            #pragma unroll
            for (int r = 0; r < 4; ++r) {
                pool0 += tanhf(acch0[r] + accl0[r] + bb0);
                pool1 += tanhf(acch1[r] + accl1[r] + bb1);
            }
        }
        #pragma unroll
        for (int ks = 0; ks < 4; ++ks) A[ks] = An[ks];
        t = tn;
    }

    // reduce over the 4 kg-duplicated lanes (rows already summed into pool regs)
    pool0 += __shfl_xor(pool0, 16, 64);
    pool0 += __shfl_xor(pool0, 32, 64);
    pool1 += __shfl_xor(pool1, 16, 64);
    pool1 += __shfl_xor(pool1, 32, 64);
    if (kg == 0) {
        atomicAdd(&pooled[fbase + nsub], pool0);
        atomicAdd(&pooled[fbase + 16 + nsub], pool1);
    }
}

// ---------------- final: vel = (pooled/N) @ Wfc + bfc, mask by in_size ----------
__global__ void k_final(const float* __restrict__ pooled, const float* __restrict__ Wfc,
                        const float* __restrict__ bfc, const int* __restrict__ in_size,
                        float* __restrict__ out) {
    int t = threadIdx.x;
    if (t >= RR * OUTF) return;
    const float invn = 1.0f / (float)NN;
    float a = bfc[t];
    for (int k = 0; k < H; ++k) a += (pooled[k] * invn) * Wfc[k * (RR * OUTF) + t];
    int r = t >> 1;
    out[t] = (r < *in_size) ? a : 0.f;
}

extern "C" void kernel_launch(void* const* d_in, const int* in_sizes, int n_in,
                              void* d_out, int out_size, void* d_ws, size_t ws_size,
                              hipStream_t stream) {
    const float* x   = (const float*)d_in[0];
    const int*   ei  = (const int*)d_in[1];     // [2, E]
    const float* W1  = (const float*)d_in[3];
    const float* b1  = (const float*)d_in[4];
    const float* W2  = (const float*)d_in[5];
    const float* b2  = (const float*)d_in[6];
    const float* Wfc = (const float*)d_in[7];
    const float* bfc = (const float*)d_in[8];
    float* out = (float*)d_out;

    const int* srcp = ei;
    const int* dstp = ei + NE;

    // workspace layout (512B aligned chunks)
    char* ws = (char*)d_ws;
    size_t off = 0;
    auto alloc = [&](size_t bytes) { void* p = ws + off; off += (bytes + 511) & ~(size_t)511; return p; };
    float*  pooled  = (float*)alloc(H * 4);       // zeroed by memset below
    int*    in_size = (int*)alloc(64);            // adjacent chunk -> one memset
    int*    histG   = (int*)alloc((size_t)NBLK * NBP * 4);    // 307 KB
    int*    offs    = (int*)alloc((size_t)NBLK * NBP * 4);    // 307 KB
    int*    bbase   = (int*)alloc(((size_t)NB + 1) * 4);
    uint32* data    = (uint32*)alloc((size_t)NE * 4);         // 6.4 MB exact
    float*  dinv    = (float*)alloc((size_t)NN * 4);
    float4* xd      = (float4*)alloc((size_t)NN * 16);        // x*dinv, L2-resident
    int*    csr_off = (int*)alloc((size_t)NN * 4);
    int*    csr_cnt = (int*)alloc((size_t)NN * 4);
    int*    csr_src = (int*)alloc((size_t)NE * 4);            // 6.4 MB
    uint32* Yp      = (uint32*)alloc((size_t)NN * 64 * 4);    // packed fp16, premult dinv
    uint32* Zp      = (uint32*)alloc((size_t)NN * 64 * 4);    // packed fp16 layer-2 agg
    (void)off; (void)ws_size; (void)in_sizes; (void)n_in; (void)out_size;

    const int nbW = (NN + 3) / 4;            // 4 waves (nodes) per block

    hipMemsetAsync(pooled, 0, 1024, stream);   // pooled (512B chunk) + in_size chunk
    k_hist<<<NBLK, 256, 0, stream>>>(dstp, histG);
    k_scan<<<1, 1024, 0, stream>>>(histG, offs, bbase);
    k_scat2<<<NBLK, 256, 0, stream>>>(srcp, dstp, offs, bbase, data);
    k_build<<<NB, 256, 0, stream>>>(data, bbase, x, csr_off, csr_cnt, csr_src, dinv, xd, in_size);
    k_l1<<<NN / 16, 256, 0, stream>>>(csr_off, csr_cnt, csr_src, xd, dinv, W1, b1, Yp);
    k_aggy<<<nbW, 256, 0, stream>>>(Yp, csr_off, csr_cnt, csr_src, dinv, Zp);
    k_mm2pool<<<512, 256, 0, stream>>>(Zp, W2, b2, pooled);
    k_final<<<1, 64, 0, stream>>>(pooled, Wfc, bfc, in_size, out);
}